// Round 8
// baseline (413.097 us; speedup 1.0000x reference)
//
#include <hip/hip_runtime.h>
#include <hip/hip_bf16.h>

#define NF 128
#define NF2 256
#define NATOMS 100000
#define NGRAPH 128

#define MT 64
#define NBLK ((NATOMS + MT - 1) / MT)   // 1563 (tail block handles 32 atoms)
#define NTHR 1024                       // 16 waves

// blob layout per layer (bf16 elems): frags for 16x16x32 MFMA B-operand
#define OW1 0                 // 8ct x 4ks
#define OW2 16384
#define OA1 32768             // 8ct x 8ks
#define OA2 65536             // 16ct x 4ks (ct0-7 = s-half, ct8-15 = gate)
#define LAYER_SZ 98304

typedef __attribute__((ext_vector_type(8))) short bf16x8;
typedef __attribute__((ext_vector_type(4))) short bf16x4;
typedef __attribute__((ext_vector_type(4))) float f32x4;

static __device__ __forceinline__ float bf2f(__hip_bfloat16 x) { return __bfloat162float(x); }
static __device__ __forceinline__ __hip_bfloat16 f2bf(float x) { return __float2bfloat16(x); }
static __device__ __forceinline__ unsigned short f2bfu(float x) {
  __hip_bfloat16 h = __float2bfloat16(x);
  return *(unsigned short*)&h;
}
static __device__ __forceinline__ bf16x8 pack8(float4 lo, float4 hi) {
  union { unsigned short s[8]; bf16x8 v; } u;
  u.s[0]=f2bfu(lo.x); u.s[1]=f2bfu(lo.y); u.s[2]=f2bfu(lo.z); u.s[3]=f2bfu(lo.w);
  u.s[4]=f2bfu(hi.x); u.s[5]=f2bfu(hi.y); u.s[6]=f2bfu(hi.z); u.s[7]=f2bfu(hi.w);
  return u.v;
}
static __device__ __forceinline__ bf16x4 pack4f(f32x4 a) {
  union { unsigned short s[4]; bf16x4 v; } u;
  u.s[0]=f2bfu(a[0]); u.s[1]=f2bfu(a[1]); u.s[2]=f2bfu(a[2]); u.s[3]=f2bfu(a[3]);
  return u.v;
}
static __device__ __forceinline__ float bfs2f(short s) {
  __hip_bfloat16 h; *(short*)&h = s; return __bfloat162float(h);
}

// Swizzled LDS tile: 16B granules, granule index XORed with (row&7).
// For the hi half (granule>=16) the XOR touches only low 3 bits -> stays in half.
static __device__ __forceinline__ bf16x8 ldfrag(const __hip_bfloat16* buf, int gr, int row, int gi) {
  return *(const bf16x8*)&buf[(row*gr + (gi ^ (row & 7)))*8];
}
// Packed 4-elem (8B) store at col base multiple of 4 (off 0 or 4 in granule).
static __device__ __forceinline__ void stq(__hip_bfloat16* buf, int gr, int row, int colb, bf16x4 v) {
  int gi = colb >> 3, off = colb & 7;
  *(bf16x4*)&buf[(row*gr + (gi ^ (row & 7)))*8 + off] = v;
}

// Pre-swizzle weights into per-MFMA B-fragment order for 16x16x32:
// blob[((ct*nks + ks)*64 + lane)*8 + j] = W[ks*32 + (lane>>4)*8 + j][ct*16 + (lane&15)]
__global__ __launch_bounds__(256)
void prep_weights(const float* __restrict__ w1, const float* __restrict__ w2,
                  const float* __restrict__ a1w, const float* __restrict__ a2w,
                  __hip_bfloat16* __restrict__ blob) {
  int gid = blockIdx.x * 256 + threadIdx.x;           // 24576 total
  int layer = gid / 12288;
  int r = gid - layer * 12288;
  const float* W; int N, nks, g; __hip_bfloat16* dst;
  if (r < 2048)      { W = w1  + layer*NF*NF;  N = NF;  nks = 4; dst = blob + layer*LAYER_SZ + OW1; g = r; }
  else if (r < 4096) { W = w2  + layer*NF*NF;  N = NF;  nks = 4; dst = blob + layer*LAYER_SZ + OW2; g = r - 2048; }
  else if (r < 8192) { W = a1w + layer*NF2*NF; N = NF;  nks = 8; dst = blob + layer*LAYER_SZ + OA1; g = r - 4096; }
  else               { W = a2w + layer*NF*NF2; N = NF2; nks = 4; dst = blob + layer*LAYER_SZ + OA2; g = r - 8192; }
  int lane = g & 63;
  int ks = (g >> 6) % nks;
  int ct = g / (64 * nks);
  int k0 = ks * 32 + ((lane >> 4) << 3);
  int n  = ct * 16 + (lane & 15);
  __hip_bfloat16* o = dst + (size_t)((ct * nks + ks) * 64 + lane) * 8;
  #pragma unroll
  for (int j = 0; j < 8; ++j) o[j] = f2bf(W[(size_t)(k0 + j) * N + n]);
}

// Fused kernel: 1563 blocks x 1024 thr (16 waves), 80 KB LDS -> 2 blocks/CU
// (32 waves/CU). R7 post-mortem: phase-latency-bound (R7 halved ds_reads but
// doubled per-phase weight loads and got SLOWER -> L2 weight-load latency per
// phase dominates; no pipe >42%). Fix: MT 32->64 with the proven R6 mapping
// (1 col-tile + 2 row-tiles per wave, 4 weight frags/phase, 60 VGPR): per-atom
// barrier count -40%, per-atom phase latency halved, occupancy 24->32 waves.
// h1 folded into hbuf's n2-half (dead after B's reads; mid-B barrier) to fit
// 80 KB. Tail block guarded. Alarms: WRITE_SIZE (spill), VGPR>64 (occupancy
// granularity), LDS_Block_Size 81920 + Occupancy (2-block residency).
__global__ __launch_bounds__(NTHR, 4)
void fused_equiv(const float* __restrict__ s_g, const float* __restrict__ v_g,
                 const __hip_bfloat16* __restrict__ blob,
                 const float* __restrict__ a1b, const float* __restrict__ a2b,
                 const float* __restrict__ out_w, const float* __restrict__ out_b,
                 float* __restrict__ sc) {
  __shared__ __hip_bfloat16 vcur[3*MT*NF];   // 48 KB, v then gated v1, gr=16
  __shared__ __hip_bfloat16 hbuf[MT*NF2];    // 32 KB, lo=[s->s1->s2], hi=[n2->h1->n2'->h1'], gr=32

  const int tid  = threadIdx.x;
  const int wave = tid >> 6;                 // 0..15
  const int lane = tid & 63;
  const int l15  = lane & 15;
  const int quad = lane >> 4;
  const int a0   = blockIdx.x * MT;
  const int ct   = wave & 7;                 // col tile (feature group of 16)
  const int rtb  = (wave >> 3) * 2;          // row-tile pair base (0 or 2)
  const int fb   = ct*16 + quad*4;           // feature base this lane owns
  const int ar0  = rtb*16 + l15;             // atom row, first row-tile
  const int ar1  = ar0 + 16;                 // atom row, second row-tile

  // ---- stage: global fp32 -> bf16 swizzled LDS (coalesced 32B/lane) ----
  {
    const float4 z4 = {0.f,0.f,0.f,0.f};
    int row = tid >> 4, gi = tid & 15;       // s: 1 granule/thread (1024 total)
    float4 lo = z4, hi = z4;
    if (a0 + row < NATOMS) {
      const float* sp = s_g + (size_t)(a0+row)*NF + gi*8;
      lo = *(const float4*)sp;
      hi = *(const float4*)(sp + 4);
    }
    *(bf16x8*)&hbuf[(row*32 + (gi ^ (row & 7)))*8] = pack8(lo, hi);
    #pragma unroll
    for (int u = 0; u < 3; ++u) {            // v: 3 granules/thread (3072 total)
      int g = tid + u*1024;
      int R = g >> 4, gi2 = g & 15;          // R = atom*3 + c  (0..191)
      int at = R / 3, c = R - 3*at;
      float4 vlo = z4, vhi = z4;
      if (a0 + at < NATOMS) {
        const float* vp = v_g + (size_t)(a0+at)*3*NF + (size_t)c*NF + gi2*8;
        vlo = *(const float4*)vp;
        vhi = *(const float4*)(vp + 4);
      }
      *(bf16x8*)&vcur[((c*MT + at)*16 + (gi2 ^ (at & 7)))*8] = pack8(vlo, vhi);
    }
  }
  __syncthreads();

  // ================= Layer 1 =================
  // ---- Phase A: (v @ w2)^T -> n2 (hbuf hi-half) ----
  {
    const __hip_bfloat16* lb = blob;
    bf16x8 wf[4];
    #pragma unroll
    for (int ks = 0; ks < 4; ++ks)
      wf[ks] = *(const bf16x8*)&lb[OW2 + ((size_t)(ct*4 + ks)*64 + lane)*8];
    #pragma unroll
    for (int rt = 0; rt < 2; ++rt) {
      int arow = rt ? ar1 : ar0;
      f32x4 nq = {0.f,0.f,0.f,0.f};
      #pragma unroll
      for (int c = 0; c < 3; ++c) {
        f32x4 acc = {0.f,0.f,0.f,0.f};
        #pragma unroll
        for (int ks = 0; ks < 4; ++ks) {
          bf16x8 af = ldfrag(vcur + c*MT*NF, 16, arow, ks*4 + quad);
          acc = __builtin_amdgcn_mfma_f32_16x16x32_bf16(wf[ks], af, acc, 0, 0, 0);
        }
        #pragma unroll
        for (int i = 0; i < 4; ++i) nq[i] += acc[i]*acc[i];
      }
      f32x4 nv;
      #pragma unroll
      for (int i = 0; i < 4; ++i) nv[i] = sqrtf(nq[i]);
      stq(hbuf, 32, arow, NF + fb, pack4f(nv));
    }
  }
  __syncthreads();

  // ---- Phase B: ([s|n2] @ a1w)^T + bias, silu -> h1 (into hbuf hi-half) ----
  {
    const __hip_bfloat16* lb = blob;
    bf16x8 a1f[8];
    #pragma unroll
    for (int ks = 0; ks < 8; ++ks)
      a1f[ks] = *(const bf16x8*)&lb[OA1 + ((size_t)(ct*8 + ks)*64 + lane)*8];
    const f32x4 b1a4 = *(const f32x4*)&a1b[fb];
    f32x4 h[2];
    #pragma unroll
    for (int rt = 0; rt < 2; ++rt) {
      int arow = rt ? ar1 : ar0;
      f32x4 acc = {0.f,0.f,0.f,0.f};
      #pragma unroll
      for (int ks = 0; ks < 8; ++ks) {
        bf16x8 af = ldfrag(hbuf, 32, arow, ks*4 + quad);
        acc = __builtin_amdgcn_mfma_f32_16x16x32_bf16(a1f[ks], af, acc, 0, 0, 0);
      }
      #pragma unroll
      for (int i = 0; i < 4; ++i) {
        float x = acc[i] + b1a4[i];
        h[rt][i] = x / (1.0f + __expf(-x));
      }
    }
    __syncthreads();   // all reads of [s|n2] done -> safe to overwrite hi-half
    stq(hbuf, 32, ar0, NF + fb, pack4f(h[0]));
    stq(hbuf, 32, ar1, NF + fb, pack4f(h[1]));
  }
  __syncthreads();

  // ---- Phase C(i): s1 = h1 @ a2w (s-half) -> hbuf lo; gate g in regs ----
  f32x4 g[2];
  {
    const __hip_bfloat16* lb = blob;
    {
      bf16x8 asf[4];
      #pragma unroll
      for (int ks = 0; ks < 4; ++ks)
        asf[ks] = *(const bf16x8*)&lb[OA2 + ((size_t)(ct*4 + ks)*64 + lane)*8];
      const f32x4 b2s4 = *(const f32x4*)&a2b[fb];
      #pragma unroll
      for (int rt = 0; rt < 2; ++rt) {
        int arow = rt ? ar1 : ar0;
        f32x4 hs = {0.f,0.f,0.f,0.f};
        #pragma unroll
        for (int ks = 0; ks < 4; ++ks) {
          bf16x8 af = ldfrag(hbuf, 32, arow, 16 + ks*4 + quad);   // h1 in hi-half
          hs = __builtin_amdgcn_mfma_f32_16x16x32_bf16(asf[ks], af, hs, 0, 0, 0);
        }
        f32x4 sv;
        #pragma unroll
        for (int i = 0; i < 4; ++i) sv[i] = hs[i] + b2s4[i];
        stq(hbuf, 32, arow, fb, pack4f(sv));   // lo-half write, hi reads elsewhere
      }
    }
    {
      bf16x8 agf[4];
      #pragma unroll
      for (int ks = 0; ks < 4; ++ks)
        agf[ks] = *(const bf16x8*)&lb[OA2 + ((size_t)((ct+8)*4 + ks)*64 + lane)*8];
      const f32x4 b2g4 = *(const f32x4*)&a2b[NF + fb];
      #pragma unroll
      for (int rt = 0; rt < 2; ++rt) {
        int arow = rt ? ar1 : ar0;
        f32x4 hg = {0.f,0.f,0.f,0.f};
        #pragma unroll
        for (int ks = 0; ks < 4; ++ks) {
          bf16x8 af = ldfrag(hbuf, 32, arow, 16 + ks*4 + quad);
          hg = __builtin_amdgcn_mfma_f32_16x16x32_bf16(agf[ks], af, hg, 0, 0, 0);
        }
        #pragma unroll
        for (int i = 0; i < 4; ++i) g[rt][i] = hg[i] + b2g4[i];
      }
    }
  }

  // ---- Phase C(ii): rematerialize v1 = v @ w1 per plane, gate, write
  //      IN PLACE into vcur. read plane c -> barrier -> write plane c. ----
  {
    const __hip_bfloat16* lb = blob;
    bf16x8 wf[4];
    #pragma unroll
    for (int ks = 0; ks < 4; ++ks)
      wf[ks] = *(const bf16x8*)&lb[OW1 + ((size_t)(ct*4 + ks)*64 + lane)*8];
    #pragma unroll
    for (int c = 0; c < 3; ++c) {
      f32x4 acc0 = {0.f,0.f,0.f,0.f}, acc1 = {0.f,0.f,0.f,0.f};
      #pragma unroll
      for (int ks = 0; ks < 4; ++ks) {
        bf16x8 af0 = ldfrag(vcur + c*MT*NF, 16, ar0, ks*4 + quad);
        bf16x8 af1 = ldfrag(vcur + c*MT*NF, 16, ar1, ks*4 + quad);
        acc0 = __builtin_amdgcn_mfma_f32_16x16x32_bf16(wf[ks], af0, acc0, 0, 0, 0);
        acc1 = __builtin_amdgcn_mfma_f32_16x16x32_bf16(wf[ks], af1, acc1, 0, 0, 0);
      }
      __syncthreads();          // all reads of plane c done
      f32x4 gv0, gv1;
      #pragma unroll
      for (int i = 0; i < 4; ++i) { gv0[i] = g[0][i]*acc0[i]; gv1[i] = g[1][i]*acc1[i]; }
      stq(vcur + c*MT*NF, 16, ar0, fb, pack4f(gv0));
      stq(vcur + c*MT*NF, 16, ar1, fb, pack4f(gv1));
    }
  }
  __syncthreads();

  // ================= Layer 2 =================
  // ---- Phase A': (v1g @ w2')^T -> n2' (hbuf hi-half; h1 is dead) ----
  {
    const __hip_bfloat16* lb = blob + LAYER_SZ;
    bf16x8 wf[4];
    #pragma unroll
    for (int ks = 0; ks < 4; ++ks)
      wf[ks] = *(const bf16x8*)&lb[OW2 + ((size_t)(ct*4 + ks)*64 + lane)*8];
    #pragma unroll
    for (int rt = 0; rt < 2; ++rt) {
      int arow = rt ? ar1 : ar0;
      f32x4 nq = {0.f,0.f,0.f,0.f};
      #pragma unroll
      for (int c = 0; c < 3; ++c) {
        f32x4 acc = {0.f,0.f,0.f,0.f};
        #pragma unroll
        for (int ks = 0; ks < 4; ++ks) {
          bf16x8 af = ldfrag(vcur + c*MT*NF, 16, arow, ks*4 + quad);
          acc = __builtin_amdgcn_mfma_f32_16x16x32_bf16(wf[ks], af, acc, 0, 0, 0);
        }
        #pragma unroll
        for (int i = 0; i < 4; ++i) nq[i] += acc[i]*acc[i];
      }
      f32x4 nv;
      #pragma unroll
      for (int i = 0; i < 4; ++i) nv[i] = sqrtf(nq[i]);
      stq(hbuf, 32, arow, NF + fb, pack4f(nv));
    }
  }
  __syncthreads();

  // ---- Phase B': ([s1|n2'] @ a1w')^T + bias, silu -> h1' (hi-half) ----
  {
    const __hip_bfloat16* lb = blob + LAYER_SZ;
    bf16x8 a1f[8];
    #pragma unroll
    for (int ks = 0; ks < 8; ++ks)
      a1f[ks] = *(const bf16x8*)&lb[OA1 + ((size_t)(ct*8 + ks)*64 + lane)*8];
    const f32x4 b1g4 = *(const f32x4*)&a1b[NF + fb];
    f32x4 h[2];
    #pragma unroll
    for (int rt = 0; rt < 2; ++rt) {
      int arow = rt ? ar1 : ar0;
      f32x4 acc = {0.f,0.f,0.f,0.f};
      #pragma unroll
      for (int ks = 0; ks < 8; ++ks) {
        bf16x8 af = ldfrag(hbuf, 32, arow, ks*4 + quad);
        acc = __builtin_amdgcn_mfma_f32_16x16x32_bf16(a1f[ks], af, acc, 0, 0, 0);
      }
      #pragma unroll
      for (int i = 0; i < 4; ++i) {
        float x = acc[i] + b1g4[i];
        h[rt][i] = x / (1.0f + __expf(-x));
      }
    }
    __syncthreads();   // all reads of [s1|n2'] done
    stq(hbuf, 32, ar0, NF + fb, pack4f(h[0]));
    stq(hbuf, 32, ar1, NF + fb, pack4f(h[1]));
  }
  __syncthreads();

  // ---- Phase C': s2 = h1' @ a2w' (s-half) -> hbuf lo ----
  {
    const __hip_bfloat16* lb = blob + LAYER_SZ;
    bf16x8 asf[4];
    #pragma unroll
    for (int ks = 0; ks < 4; ++ks)
      asf[ks] = *(const bf16x8*)&lb[OA2 + ((size_t)(ct*4 + ks)*64 + lane)*8];
    const f32x4 b2s24 = *(const f32x4*)&a2b[2*NF + fb];
    #pragma unroll
    for (int rt = 0; rt < 2; ++rt) {
      int arow = rt ? ar1 : ar0;
      f32x4 hs = {0.f,0.f,0.f,0.f};
      #pragma unroll
      for (int ks = 0; ks < 4; ++ks) {
        bf16x8 af = ldfrag(hbuf, 32, arow, 16 + ks*4 + quad);
        hs = __builtin_amdgcn_mfma_f32_16x16x32_bf16(asf[ks], af, hs, 0, 0, 0);
      }
      f32x4 sv;
      #pragma unroll
      for (int i = 0; i < 4; ++i) sv[i] = hs[i] + b2s24[i];
      stq(hbuf, 32, arow, fb, pack4f(sv));
    }
  }
  __syncthreads();

  // ---- head: sc[atom] = dot(s2, out_w) + out_b (b128 LDS read) ----
  {
    int a   = tid >> 4;        // 64 atoms x 16 threads
    int sub = tid & 15;
    bf16x8 sv = ldfrag(hbuf, 32, a, sub);
    const float* owp = out_w + sub*8;
    float p = 0.f;
    #pragma unroll
    for (int j = 0; j < 8; ++j) p += bfs2f(sv[j]) * owp[j];
    p += __shfl_down(p, 8, 16);
    p += __shfl_down(p, 4, 16);
    p += __shfl_down(p, 2, 16);
    p += __shfl_down(p, 1, 16);
    if (sub == 0 && a0 + a < NATOMS) sc[a0 + a] = p + out_b[0];
  }
}

// Stage 1: partials over 16 aligned chunks per graph (2048 blocks, float4 loads)
#define CHUNK 6256   // 16B-aligned chunk (6256*4 bytes); last chunk = 6160
__global__ __launch_bounds__(256)
void reduce_partial(const float* __restrict__ mask, const float* __restrict__ sc,
                    float* __restrict__ partial) {
  int b  = blockIdx.x >> 4;
  int ch = blockIdx.x & 15;
  int n0 = ch * CHUNK;
  int n1 = n0 + CHUNK; if (n1 > NATOMS) n1 = NATOMS;
  const float4* m4 = (const float4*)(mask + (size_t)b * NATOMS + n0);
  const float4* s4 = (const float4*)(sc + n0);
  int nq = (n1 - n0) >> 2;
  float acc = 0.f;
  for (int i = threadIdx.x; i < nq; i += 256) {
    float4 m = m4[i], s = s4[i];
    acc += m.x*s.x + m.y*s.y + m.z*s.z + m.w*s.w;
  }
  #pragma unroll
  for (int d = 32; d > 0; d >>= 1) acc += __shfl_down(acc, d, 64);
  __shared__ float red[4];
  if ((threadIdx.x & 63) == 0) red[threadIdx.x >> 6] = acc;
  __syncthreads();
  if (threadIdx.x == 0) partial[blockIdx.x] = red[0] + red[1] + red[2] + red[3];
}

__global__ void reduce_final(const float* __restrict__ partial, float* __restrict__ out) {
  int b = threadIdx.x;
  if (b < NGRAPH) {
    float s = 0.f;
    #pragma unroll
    for (int k = 0; k < 16; ++k) s += partial[b*16 + k];
    out[b] = s;
  }
}

extern "C" void kernel_launch(void* const* d_in, const int* in_sizes, int n_in,
                              void* d_out, int out_size, void* d_ws, size_t ws_size,
                              hipStream_t stream) {
  const float* s    = (const float*)d_in[0];
  const float* v    = (const float*)d_in[1];
  // d_in[2] = r, unused
  const float* mask = (const float*)d_in[3];
  const float* w1   = (const float*)d_in[4];
  const float* w2   = (const float*)d_in[5];
  const float* a1w  = (const float*)d_in[6];
  const float* a1b  = (const float*)d_in[7];
  const float* a2w  = (const float*)d_in[8];
  const float* a2b  = (const float*)d_in[9];
  const float* outw = (const float*)d_in[10];
  const float* outb = (const float*)d_in[11];

  char* ws = (char*)d_ws;
  __hip_bfloat16* blob = (__hip_bfloat16*)ws;                      // 384 KB
  float* sc      = (float*)(ws + (size_t)2*LAYER_SZ*2);            // 400 KB
  float* partial = (float*)(ws + (size_t)2*LAYER_SZ*2 + NATOMS*4); // 8 KB

  prep_weights<<<96, 256, 0, stream>>>(w1, w2, a1w, a2w, blob);
  fused_equiv<<<NBLK, NTHR, 0, stream>>>(s, v, blob, a1b, a2b, outw, outb, sc);
  reduce_partial<<<NGRAPH*16, 256, 0, stream>>>(mask, sc, partial);
  reduce_final<<<1, 128, 0, stream>>>(partial, (float*)d_out);
}

// Round 9
// 353.984 us; speedup vs baseline: 1.1670x; 1.1670x over previous
//
#include <hip/hip_runtime.h>
#include <hip/hip_bf16.h>

#define NF 128
#define NF2 256
#define NATOMS 100000
#define NGRAPH 128

#define MT 32
#define NBLK (NATOMS/MT)      // 3125
#define NTHR 512              // 8 waves

// blob layout per layer (bf16 elems): frags for 16x16x32 MFMA B-operand
#define OW1 0                 // 8ct x 4ks
#define OW2 16384
#define OA1 32768             // 8ct x 8ks
#define OA2 65536             // 16ct x 4ks (ct0-7 = s-half, ct8-15 = gate)
#define LAYER_SZ 98304

typedef __attribute__((ext_vector_type(8))) short bf16x8;
typedef __attribute__((ext_vector_type(4))) short bf16x4;
typedef __attribute__((ext_vector_type(4))) float f32x4;

static __device__ __forceinline__ float bf2f(__hip_bfloat16 x) { return __bfloat162float(x); }
static __device__ __forceinline__ __hip_bfloat16 f2bf(float x) { return __float2bfloat16(x); }
static __device__ __forceinline__ unsigned short f2bfu(float x) {
  __hip_bfloat16 h = __float2bfloat16(x);
  return *(unsigned short*)&h;
}
static __device__ __forceinline__ bf16x8 pack8(float4 lo, float4 hi) {
  union { unsigned short s[8]; bf16x8 v; } u;
  u.s[0]=f2bfu(lo.x); u.s[1]=f2bfu(lo.y); u.s[2]=f2bfu(lo.z); u.s[3]=f2bfu(lo.w);
  u.s[4]=f2bfu(hi.x); u.s[5]=f2bfu(hi.y); u.s[6]=f2bfu(hi.z); u.s[7]=f2bfu(hi.w);
  return u.v;
}
static __device__ __forceinline__ bf16x4 pack4f(f32x4 a) {
  union { unsigned short s[4]; bf16x4 v; } u;
  u.s[0]=f2bfu(a[0]); u.s[1]=f2bfu(a[1]); u.s[2]=f2bfu(a[2]); u.s[3]=f2bfu(a[3]);
  return u.v;
}
static __device__ __forceinline__ float bfs2f(short s) {
  __hip_bfloat16 h; *(short*)&h = s; return __bfloat162float(h);
}

// Swizzled LDS tile: 16B granules, granule index XORed with (row&7).
// XOR touches only low 3 bits of gi -> granules stay within their 16-granule half.
static __device__ __forceinline__ bf16x8 ldfrag(const __hip_bfloat16* buf, int gr, int row, int gi) {
  return *(const bf16x8*)&buf[(row*gr + (gi ^ (row & 7)))*8];
}
// Packed 4-elem (8B) store at col base multiple of 4 (off 0 or 4 in granule).
static __device__ __forceinline__ void stq(__hip_bfloat16* buf, int gr, int row, int colb, bf16x4 v) {
  int gi = colb >> 3, off = colb & 7;
  *(bf16x4*)&buf[(row*gr + (gi ^ (row & 7)))*8 + off] = v;
}

// Pre-swizzle weights into per-MFMA B-fragment order for 16x16x32:
// blob[((ct*nks + ks)*64 + lane)*8 + j] = W[ks*32 + (lane>>4)*8 + j][ct*16 + (lane&15)]
__global__ __launch_bounds__(256)
void prep_weights(const float* __restrict__ w1, const float* __restrict__ w2,
                  const float* __restrict__ a1w, const float* __restrict__ a2w,
                  __hip_bfloat16* __restrict__ blob) {
  int gid = blockIdx.x * 256 + threadIdx.x;           // 24576 total
  int layer = gid / 12288;
  int r = gid - layer * 12288;
  const float* W; int N, nks, g; __hip_bfloat16* dst;
  if (r < 2048)      { W = w1  + layer*NF*NF;  N = NF;  nks = 4; dst = blob + layer*LAYER_SZ + OW1; g = r; }
  else if (r < 4096) { W = w2  + layer*NF*NF;  N = NF;  nks = 4; dst = blob + layer*LAYER_SZ + OW2; g = r - 2048; }
  else if (r < 8192) { W = a1w + layer*NF2*NF; N = NF;  nks = 8; dst = blob + layer*LAYER_SZ + OA1; g = r - 4096; }
  else               { W = a2w + layer*NF*NF2; N = NF2; nks = 4; dst = blob + layer*LAYER_SZ + OA2; g = r - 8192; }
  int lane = g & 63;
  int ks = (g >> 6) % nks;
  int ct = g / (64 * nks);
  int k0 = ks * 32 + ((lane >> 4) << 3);
  int n  = ct * 16 + (lane & 15);
  __hip_bfloat16* o = dst + (size_t)((ct * nks + ks) * 64 + lane) * 8;
  #pragma unroll
  for (int j = 0; j < 8; ++j) o[j] = f2bf(W[(size_t)(k0 + j) * N + n]);
}

// Fused kernel: 3125 blocks x 512 thr (8 waves), 40 KB LDS -> 4 blocks/CU
// (32 waves = full). R8 post-mortem: MT=64/80KB got only 1 block resident
// (occ 41% unchanged) -> dead end; R6 (137us, 48KB, 3 blocks) is the best
// structure. This round: R6 geometry + R8's proven h1->hbuf-hi fold, which
// cuts LDS 48->40KB for 4 blocks/CU at the cost of 2 mid-phase barriers.
// Layer-2 ping-pong: s1->lo, n2'->hi (h1 dead), h1'->hi, s2->lo; the
// [s1|n2'] concat k-order stays correct. Alarms: VGPR>64 (drops a block),
// WRITE_SIZE (spill), Occupancy ~41% => LDS exact-fit reservation.
__global__ __launch_bounds__(NTHR, 4)
void fused_equiv(const float* __restrict__ s_g, const float* __restrict__ v_g,
                 const __hip_bfloat16* __restrict__ blob,
                 const float* __restrict__ a1b, const float* __restrict__ a2b,
                 const float* __restrict__ out_w, const float* __restrict__ out_b,
                 float* __restrict__ sc) {
  __shared__ __hip_bfloat16 vcur[3*MT*NF];   // 24 KB, v then gated v1, gr=16
  __shared__ __hip_bfloat16 hbuf[MT*NF2];    // 16 KB, lo=[s,s1,s2], hi=[n2,h1,n2',h1'], gr=32

  const int tid  = threadIdx.x;
  const int wave = tid >> 6;                 // 0..7
  const int lane = tid & 63;
  const int l15  = lane & 15;
  const int quad = lane >> 4;
  const int a0   = blockIdx.x * MT;
  const int ct   = wave;                     // col tile (feature group of 16)
  const int fb   = ct*16 + quad*4;           // feature base this lane owns

  // ---- stage: global fp32 -> bf16 swizzled LDS (coalesced 32B/lane) ----
  {
    int row = tid >> 4, gi = tid & 15;       // s: 1 granule/thread (512 total)
    const float* sp = s_g + (size_t)a0*NF + row*NF + gi*8;
    float4 lo = *(const float4*)sp;
    float4 hi = *(const float4*)(sp + 4);
    *(bf16x8*)&hbuf[(row*32 + (gi ^ (row & 7)))*8] = pack8(lo, hi);
    #pragma unroll
    for (int u = 0; u < 3; ++u) {            // v: 3 granules/thread (1536 total)
      int g = tid + u*512;
      int R = g >> 4, gi2 = g & 15;          // R = atom*3 + c
      int at = R / 3, c = R - 3*at;
      const float* vp = v_g + (size_t)a0*3*NF + R*NF + gi2*8;
      float4 vlo = *(const float4*)vp;
      float4 vhi = *(const float4*)(vp + 4);
      *(bf16x8*)&vcur[((c*MT + at)*16 + (gi2 ^ (at & 7)))*8] = pack8(vlo, vhi);
    }
  }
  __syncthreads();

  // ================= Layer 1 =================
  // ---- Phase A: (v @ w2)^T -> n2 (hbuf hi-half) ----
  {
    const __hip_bfloat16* lb = blob;
    bf16x8 wf[4];
    #pragma unroll
    for (int ks = 0; ks < 4; ++ks)
      wf[ks] = *(const bf16x8*)&lb[OW2 + ((size_t)(ct*4 + ks)*64 + lane)*8];
    #pragma unroll
    for (int rt = 0; rt < 2; ++rt) {
      int arow = rt*16 + l15;
      f32x4 nq = {0.f,0.f,0.f,0.f};
      #pragma unroll
      for (int c = 0; c < 3; ++c) {
        f32x4 acc = {0.f,0.f,0.f,0.f};
        #pragma unroll
        for (int ks = 0; ks < 4; ++ks) {
          bf16x8 af = ldfrag(vcur + c*MT*NF, 16, arow, ks*4 + quad);
          acc = __builtin_amdgcn_mfma_f32_16x16x32_bf16(wf[ks], af, acc, 0, 0, 0);
        }
        #pragma unroll
        for (int i = 0; i < 4; ++i) nq[i] += acc[i]*acc[i];
      }
      f32x4 nv;
      #pragma unroll
      for (int i = 0; i < 4; ++i) nv[i] = sqrtf(nq[i]);
      stq(hbuf, 32, arow, NF + fb, pack4f(nv));
    }
  }
  __syncthreads();

  // ---- Phase B: ([s|n2] @ a1w)^T + bias, silu -> h1 (hbuf hi, after mid-bar) ----
  {
    const __hip_bfloat16* lb = blob;
    bf16x8 a1f[8];
    #pragma unroll
    for (int ks = 0; ks < 8; ++ks)
      a1f[ks] = *(const bf16x8*)&lb[OA1 + ((size_t)(ct*8 + ks)*64 + lane)*8];
    const f32x4 b1a4 = *(const f32x4*)&a1b[fb];
    f32x4 h[2];
    #pragma unroll
    for (int rt = 0; rt < 2; ++rt) {
      int arow = rt*16 + l15;
      f32x4 acc = {0.f,0.f,0.f,0.f};
      #pragma unroll
      for (int ks = 0; ks < 8; ++ks) {
        bf16x8 af = ldfrag(hbuf, 32, arow, ks*4 + quad);
        acc = __builtin_amdgcn_mfma_f32_16x16x32_bf16(a1f[ks], af, acc, 0, 0, 0);
      }
      #pragma unroll
      for (int i = 0; i < 4; ++i) {
        float x = acc[i] + b1a4[i];
        h[rt][i] = x / (1.0f + __expf(-x));
      }
    }
    __syncthreads();   // all reads of [s|n2] done -> safe to overwrite hi-half
    stq(hbuf, 32,      l15, NF + fb, pack4f(h[0]));
    stq(hbuf, 32, 16 + l15, NF + fb, pack4f(h[1]));
  }
  __syncthreads();

  // ---- Phase C(i): s1 = h1 @ a2w (s-half) -> hbuf lo; gate g in regs ----
  f32x4 g[2];
  {
    const __hip_bfloat16* lb = blob;
    {
      bf16x8 asf[4];
      #pragma unroll
      for (int ks = 0; ks < 4; ++ks)
        asf[ks] = *(const bf16x8*)&lb[OA2 + ((size_t)(ct*4 + ks)*64 + lane)*8];
      const f32x4 b2s4 = *(const f32x4*)&a2b[fb];
      #pragma unroll
      for (int rt = 0; rt < 2; ++rt) {
        int arow = rt*16 + l15;
        f32x4 hs = {0.f,0.f,0.f,0.f};
        #pragma unroll
        for (int ks = 0; ks < 4; ++ks) {
          bf16x8 af = ldfrag(hbuf, 32, arow, 16 + ks*4 + quad);   // h1 in hi-half
          hs = __builtin_amdgcn_mfma_f32_16x16x32_bf16(asf[ks], af, hs, 0, 0, 0);
        }
        f32x4 sv;
        #pragma unroll
        for (int i = 0; i < 4; ++i) sv[i] = hs[i] + b2s4[i];
        stq(hbuf, 32, arow, fb, pack4f(sv));   // lo-half write; s is dead
      }
    }
    {
      bf16x8 agf[4];
      #pragma unroll
      for (int ks = 0; ks < 4; ++ks)
        agf[ks] = *(const bf16x8*)&lb[OA2 + ((size_t)((ct+8)*4 + ks)*64 + lane)*8];
      const f32x4 b2g4 = *(const f32x4*)&a2b[NF + fb];
      #pragma unroll
      for (int rt = 0; rt < 2; ++rt) {
        int arow = rt*16 + l15;
        f32x4 hg = {0.f,0.f,0.f,0.f};
        #pragma unroll
        for (int ks = 0; ks < 4; ++ks) {
          bf16x8 af = ldfrag(hbuf, 32, arow, 16 + ks*4 + quad);
          hg = __builtin_amdgcn_mfma_f32_16x16x32_bf16(agf[ks], af, hg, 0, 0, 0);
        }
        #pragma unroll
        for (int i = 0; i < 4; ++i) g[rt][i] = hg[i] + b2g4[i];
      }
    }
  }

  // ---- Phase C(ii): rematerialize v1 = v @ w1 per plane, gate, write
  //      IN PLACE into vcur. read plane c -> barrier -> write plane c. ----
  {
    const __hip_bfloat16* lb = blob;
    bf16x8 wf[4];
    #pragma unroll
    for (int ks = 0; ks < 4; ++ks)
      wf[ks] = *(const bf16x8*)&lb[OW1 + ((size_t)(ct*4 + ks)*64 + lane)*8];
    #pragma unroll
    for (int c = 0; c < 3; ++c) {
      f32x4 acc0 = {0.f,0.f,0.f,0.f}, acc1 = {0.f,0.f,0.f,0.f};
      #pragma unroll
      for (int ks = 0; ks < 4; ++ks) {
        bf16x8 af0 = ldfrag(vcur + c*MT*NF, 16, l15,      ks*4 + quad);
        bf16x8 af1 = ldfrag(vcur + c*MT*NF, 16, 16 + l15, ks*4 + quad);
        acc0 = __builtin_amdgcn_mfma_f32_16x16x32_bf16(wf[ks], af0, acc0, 0, 0, 0);
        acc1 = __builtin_amdgcn_mfma_f32_16x16x32_bf16(wf[ks], af1, acc1, 0, 0, 0);
      }
      __syncthreads();          // all reads of plane c done
      f32x4 gv0, gv1;
      #pragma unroll
      for (int i = 0; i < 4; ++i) { gv0[i] = g[0][i]*acc0[i]; gv1[i] = g[1][i]*acc1[i]; }
      stq(vcur + c*MT*NF, 16, l15,      fb, pack4f(gv0));
      stq(vcur + c*MT*NF, 16, 16 + l15, fb, pack4f(gv1));
    }
  }
  __syncthreads();

  // ================= Layer 2 =================
  // ---- Phase A': (v1g @ w2')^T -> n2' (hbuf hi; h1 dead after C(i)) ----
  {
    const __hip_bfloat16* lb = blob + LAYER_SZ;
    bf16x8 wf[4];
    #pragma unroll
    for (int ks = 0; ks < 4; ++ks)
      wf[ks] = *(const bf16x8*)&lb[OW2 + ((size_t)(ct*4 + ks)*64 + lane)*8];
    #pragma unroll
    for (int rt = 0; rt < 2; ++rt) {
      int arow = rt*16 + l15;
      f32x4 nq = {0.f,0.f,0.f,0.f};
      #pragma unroll
      for (int c = 0; c < 3; ++c) {
        f32x4 acc = {0.f,0.f,0.f,0.f};
        #pragma unroll
        for (int ks = 0; ks < 4; ++ks) {
          bf16x8 af = ldfrag(vcur + c*MT*NF, 16, arow, ks*4 + quad);
          acc = __builtin_amdgcn_mfma_f32_16x16x32_bf16(wf[ks], af, acc, 0, 0, 0);
        }
        #pragma unroll
        for (int i = 0; i < 4; ++i) nq[i] += acc[i]*acc[i];
      }
      f32x4 nv;
      #pragma unroll
      for (int i = 0; i < 4; ++i) nv[i] = sqrtf(nq[i]);
      stq(hbuf, 32, arow, NF + fb, pack4f(nv));
    }
  }
  __syncthreads();

  // ---- Phase B': ([s1|n2'] @ a1w')^T + bias, silu -> h1' (hi, after mid-bar) ----
  {
    const __hip_bfloat16* lb = blob + LAYER_SZ;
    bf16x8 a1f[8];
    #pragma unroll
    for (int ks = 0; ks < 8; ++ks)
      a1f[ks] = *(const bf16x8*)&lb[OA1 + ((size_t)(ct*8 + ks)*64 + lane)*8];
    const f32x4 b1g4 = *(const f32x4*)&a1b[NF + fb];
    f32x4 h[2];
    #pragma unroll
    for (int rt = 0; rt < 2; ++rt) {
      int arow = rt*16 + l15;
      f32x4 acc = {0.f,0.f,0.f,0.f};
      #pragma unroll
      for (int ks = 0; ks < 8; ++ks) {
        bf16x8 af = ldfrag(hbuf, 32, arow, ks*4 + quad);   // lo=s1, hi=n2'
        acc = __builtin_amdgcn_mfma_f32_16x16x32_bf16(a1f[ks], af, acc, 0, 0, 0);
      }
      #pragma unroll
      for (int i = 0; i < 4; ++i) {
        float x = acc[i] + b1g4[i];
        h[rt][i] = x / (1.0f + __expf(-x));
      }
    }
    __syncthreads();   // all reads of [s1|n2'] done
    stq(hbuf, 32,      l15, NF + fb, pack4f(h[0]));
    stq(hbuf, 32, 16 + l15, NF + fb, pack4f(h[1]));
  }
  __syncthreads();

  // ---- Phase C': s2 = h1' @ a2w' (s-half) -> hbuf lo ----
  {
    const __hip_bfloat16* lb = blob + LAYER_SZ;
    bf16x8 asf[4];
    #pragma unroll
    for (int ks = 0; ks < 4; ++ks)
      asf[ks] = *(const bf16x8*)&lb[OA2 + ((size_t)(ct*4 + ks)*64 + lane)*8];
    const f32x4 b2s24 = *(const f32x4*)&a2b[2*NF + fb];
    #pragma unroll
    for (int rt = 0; rt < 2; ++rt) {
      int arow = rt*16 + l15;
      f32x4 hs = {0.f,0.f,0.f,0.f};
      #pragma unroll
      for (int ks = 0; ks < 4; ++ks) {
        bf16x8 af = ldfrag(hbuf, 32, arow, 16 + ks*4 + quad);
        hs = __builtin_amdgcn_mfma_f32_16x16x32_bf16(asf[ks], af, hs, 0, 0, 0);
      }
      f32x4 sv;
      #pragma unroll
      for (int i = 0; i < 4; ++i) sv[i] = hs[i] + b2s24[i];
      stq(hbuf, 32, arow, fb, pack4f(sv));
    }
  }
  __syncthreads();

  // ---- head: sc[atom] = dot(s2, out_w) + out_b (b128 LDS read) ----
  {
    int a   = tid >> 4;        // 32 atoms x 16 threads
    int sub = tid & 15;
    bf16x8 sv = ldfrag(hbuf, 32, a, sub);
    const float* owp = out_w + sub*8;
    float p = 0.f;
    #pragma unroll
    for (int j = 0; j < 8; ++j) p += bfs2f(sv[j]) * owp[j];
    p += __shfl_down(p, 8, 16);
    p += __shfl_down(p, 4, 16);
    p += __shfl_down(p, 2, 16);
    p += __shfl_down(p, 1, 16);
    if (sub == 0) sc[a0 + a] = p + out_b[0];
  }
}

// Stage 1: partials over 16 aligned chunks per graph (2048 blocks, float4 loads)
#define CHUNK 6256   // 16B-aligned chunk (6256*4 bytes); last chunk = 6160
__global__ __launch_bounds__(256)
void reduce_partial(const float* __restrict__ mask, const float* __restrict__ sc,
                    float* __restrict__ partial) {
  int b  = blockIdx.x >> 4;
  int ch = blockIdx.x & 15;
  int n0 = ch * CHUNK;
  int n1 = n0 + CHUNK; if (n1 > NATOMS) n1 = NATOMS;
  const float4* m4 = (const float4*)(mask + (size_t)b * NATOMS + n0);
  const float4* s4 = (const float4*)(sc + n0);
  int nq = (n1 - n0) >> 2;
  float acc = 0.f;
  for (int i = threadIdx.x; i < nq; i += 256) {
    float4 m = m4[i], s = s4[i];
    acc += m.x*s.x + m.y*s.y + m.z*s.z + m.w*s.w;
  }
  #pragma unroll
  for (int d = 32; d > 0; d >>= 1) acc += __shfl_down(acc, d, 64);
  __shared__ float red[4];
  if ((threadIdx.x & 63) == 0) red[threadIdx.x >> 6] = acc;
  __syncthreads();
  if (threadIdx.x == 0) partial[blockIdx.x] = red[0] + red[1] + red[2] + red[3];
}

__global__ void reduce_final(const float* __restrict__ partial, float* __restrict__ out) {
  int b = threadIdx.x;
  if (b < NGRAPH) {
    float s = 0.f;
    #pragma unroll
    for (int k = 0; k < 16; ++k) s += partial[b*16 + k];
    out[b] = s;
  }
}

extern "C" void kernel_launch(void* const* d_in, const int* in_sizes, int n_in,
                              void* d_out, int out_size, void* d_ws, size_t ws_size,
                              hipStream_t stream) {
  const float* s    = (const float*)d_in[0];
  const float* v    = (const float*)d_in[1];
  // d_in[2] = r, unused
  const float* mask = (const float*)d_in[3];
  const float* w1   = (const float*)d_in[4];
  const float* w2   = (const float*)d_in[5];
  const float* a1w  = (const float*)d_in[6];
  const float* a1b  = (const float*)d_in[7];
  const float* a2w  = (const float*)d_in[8];
  const float* a2b  = (const float*)d_in[9];
  const float* outw = (const float*)d_in[10];
  const float* outb = (const float*)d_in[11];

  char* ws = (char*)d_ws;
  __hip_bfloat16* blob = (__hip_bfloat16*)ws;                      // 384 KB
  float* sc      = (float*)(ws + (size_t)2*LAYER_SZ*2);            // 400 KB
  float* partial = (float*)(ws + (size_t)2*LAYER_SZ*2 + NATOMS*4); // 8 KB

  prep_weights<<<96, 256, 0, stream>>>(w1, w2, a1w, a2w, blob);
  fused_equiv<<<NBLK, NTHR, 0, stream>>>(s, v, blob, a1b, a2b, outw, outb, sc);
  reduce_partial<<<NGRAPH*16, 256, 0, stream>>>(mask, sc, partial);
  reduce_final<<<1, 128, 0, stream>>>(partial, (float*)d_out);
}

// Round 10
// 352.268 us; speedup vs baseline: 1.1727x; 1.0049x over previous
//
#include <hip/hip_runtime.h>
#include <hip/hip_bf16.h>

#define NF 128
#define NF2 256
#define NATOMS 100000
#define NGRAPH 128

#define MT 32
#define NBLK (NATOMS/MT)      // 3125
#define NTHR 512              // 8 waves

// blob layout per layer (bf16 elems): frags for 16x16x32 MFMA B-operand
#define OW1 0                 // 8ct x 4ks
#define OW2 16384
#define OA1 32768             // 8ct x 8ks
#define OA2 65536             // 16ct x 4ks (ct0-7 = s-half, ct8-15 = gate)
#define LAYER_SZ 98304

typedef __attribute__((ext_vector_type(8))) short bf16x8;
typedef __attribute__((ext_vector_type(4))) short bf16x4;
typedef __attribute__((ext_vector_type(4))) float f32x4;

static __device__ __forceinline__ float bf2f(__hip_bfloat16 x) { return __bfloat162float(x); }
static __device__ __forceinline__ __hip_bfloat16 f2bf(float x) { return __float2bfloat16(x); }
static __device__ __forceinline__ unsigned short f2bfu(float x) {
  __hip_bfloat16 h = __float2bfloat16(x);
  return *(unsigned short*)&h;
}
static __device__ __forceinline__ bf16x8 pack8(float4 lo, float4 hi) {
  union { unsigned short s[8]; bf16x8 v; } u;
  u.s[0]=f2bfu(lo.x); u.s[1]=f2bfu(lo.y); u.s[2]=f2bfu(lo.z); u.s[3]=f2bfu(lo.w);
  u.s[4]=f2bfu(hi.x); u.s[5]=f2bfu(hi.y); u.s[6]=f2bfu(hi.z); u.s[7]=f2bfu(hi.w);
  return u.v;
}
static __device__ __forceinline__ bf16x4 pack4f(f32x4 a) {
  union { unsigned short s[4]; bf16x4 v; } u;
  u.s[0]=f2bfu(a[0]); u.s[1]=f2bfu(a[1]); u.s[2]=f2bfu(a[2]); u.s[3]=f2bfu(a[3]);
  return u.v;
}

// Swizzled LDS tile: 16B granules, granule index XORed with (row&7).
static __device__ __forceinline__ bf16x8 ldfrag(const __hip_bfloat16* buf, int gr, int row, int gi) {
  return *(const bf16x8*)&buf[(row*gr + (gi ^ (row & 7)))*8];
}
// Packed 4-elem (8B) store at col base multiple of 4 (off 0 or 4 in granule).
static __device__ __forceinline__ void stq(__hip_bfloat16* buf, int gr, int row, int colb, bf16x4 v) {
  int gi = colb >> 3, off = colb & 7;
  *(bf16x4*)&buf[(row*gr + (gi ^ (row & 7)))*8 + off] = v;
}

// Pre-swizzle weights into per-MFMA B-fragment order for 16x16x32:
// blob[((ct*nks + ks)*64 + lane)*8 + j] = W[ks*32 + (lane>>4)*8 + j][ct*16 + (lane&15)]
// Block 96 additionally builds the folded head: u = a2w'[s-half] @ out_w (128 f32)
// and uc[128] = b2s2 . out_w + out_b.
__global__ __launch_bounds__(256)
void prep_weights(const float* __restrict__ w1, const float* __restrict__ w2,
                  const float* __restrict__ a1w, const float* __restrict__ a2w,
                  const float* __restrict__ a2b, const float* __restrict__ outw,
                  const float* __restrict__ outb,
                  __hip_bfloat16* __restrict__ blob, float* __restrict__ uc) {
  if (blockIdx.x == 96) {
    int f = threadIdx.x;
    if (f < NF) {
      const float* A = a2w + (size_t)NF*NF2 + (size_t)f*NF2;   // layer-1 (2nd) a2w, row f, s-half
      float acc = 0.f;
      #pragma unroll 8
      for (int g = 0; g < NF; ++g) acc += A[g] * outw[g];
      uc[f] = acc;
    }
    if (f == NF) {
      float c = outb[0];
      for (int g = 0; g < NF; ++g) c += a2b[2*NF + g] * outw[g];
      uc[NF] = c;
    }
    return;
  }
  int gid = blockIdx.x * 256 + threadIdx.x;           // 24576 total
  int layer = gid / 12288;
  int r = gid - layer * 12288;
  const float* W; int N, nks, g; __hip_bfloat16* dst;
  if (r < 2048)      { W = w1  + layer*NF*NF;  N = NF;  nks = 4; dst = blob + layer*LAYER_SZ + OW1; g = r; }
  else if (r < 4096) { W = w2  + layer*NF*NF;  N = NF;  nks = 4; dst = blob + layer*LAYER_SZ + OW2; g = r - 2048; }
  else if (r < 8192) { W = a1w + layer*NF2*NF; N = NF;  nks = 8; dst = blob + layer*LAYER_SZ + OA1; g = r - 4096; }
  else               { W = a2w + layer*NF*NF2; N = NF2; nks = 4; dst = blob + layer*LAYER_SZ + OA2; g = r - 8192; }
  int lane = g & 63;
  int ks = (g >> 6) % nks;
  int ct = g / (64 * nks);
  int k0 = ks * 32 + ((lane >> 4) << 3);
  int n  = ct * 16 + (lane & 15);
  __hip_bfloat16* o = dst + (size_t)((ct * nks + ks) * 64 + lane) * 8;
  #pragma unroll
  for (int j = 0; j < 8; ++j) o[j] = f2bf(W[(size_t)(k0 + j) * N + n]);
}

// Fused kernel: 3125 blocks x 512 thr (8 waves), 40 KB LDS.
// R9 post-mortem: 2/3/4 resident blocks all land at 137-142us -> latency
// hiding saturated; remaining lever is removing work. This round: HEAD FOLD.
// sc = (h1' @ a2w'_s) . ow + b = h1' . (a2w'_s @ ow) + const, so Phase C'
// (8 MFMA + 8 ds_read + 4 wloads + stores) and the old head collapse into
// 8 FMAs on B''s register-resident h1' + a padded-LDS partial reduce.
// One barrier removed. Everything else identical to R9.
__global__ __launch_bounds__(NTHR, 4)
void fused_equiv(const float* __restrict__ s_g, const float* __restrict__ v_g,
                 const __hip_bfloat16* __restrict__ blob,
                 const float* __restrict__ a1b, const float* __restrict__ a2b,
                 const float* __restrict__ uc,
                 float* __restrict__ sc) {
  __shared__ __hip_bfloat16 vcur[3*MT*NF];   // 24 KB, v then gated v1, gr=16
  __shared__ __hip_bfloat16 hbuf[MT*NF2];    // 16 KB, lo=[s,s1]+part, hi=[n2,h1,n2'], gr=32

  const int tid  = threadIdx.x;
  const int wave = tid >> 6;                 // 0..7
  const int lane = tid & 63;
  const int l15  = lane & 15;
  const int quad = lane >> 4;
  const int a0   = blockIdx.x * MT;
  const int ct   = wave;                     // col tile (feature group of 16)
  const int fb   = ct*16 + quad*4;           // feature base this lane owns

  // ---- stage: global fp32 -> bf16 swizzled LDS (coalesced 32B/lane) ----
  {
    int row = tid >> 4, gi = tid & 15;       // s: 1 granule/thread (512 total)
    const float* sp = s_g + (size_t)a0*NF + row*NF + gi*8;
    float4 lo = *(const float4*)sp;
    float4 hi = *(const float4*)(sp + 4);
    *(bf16x8*)&hbuf[(row*32 + (gi ^ (row & 7)))*8] = pack8(lo, hi);
    #pragma unroll
    for (int u = 0; u < 3; ++u) {            // v: 3 granules/thread (1536 total)
      int g = tid + u*512;
      int R = g >> 4, gi2 = g & 15;          // R = atom*3 + c
      int at = R / 3, c = R - 3*at;
      const float* vp = v_g + (size_t)a0*3*NF + R*NF + gi2*8;
      float4 vlo = *(const float4*)vp;
      float4 vhi = *(const float4*)(vp + 4);
      *(bf16x8*)&vcur[((c*MT + at)*16 + (gi2 ^ (at & 7)))*8] = pack8(vlo, vhi);
    }
  }
  __syncthreads();

  // ================= Layer 1 =================
  // ---- Phase A: (v @ w2)^T -> n2 (hbuf hi-half) ----
  {
    const __hip_bfloat16* lb = blob;
    bf16x8 wf[4];
    #pragma unroll
    for (int ks = 0; ks < 4; ++ks)
      wf[ks] = *(const bf16x8*)&lb[OW2 + ((size_t)(ct*4 + ks)*64 + lane)*8];
    #pragma unroll
    for (int rt = 0; rt < 2; ++rt) {
      int arow = rt*16 + l15;
      f32x4 nq = {0.f,0.f,0.f,0.f};
      #pragma unroll
      for (int c = 0; c < 3; ++c) {
        f32x4 acc = {0.f,0.f,0.f,0.f};
        #pragma unroll
        for (int ks = 0; ks < 4; ++ks) {
          bf16x8 af = ldfrag(vcur + c*MT*NF, 16, arow, ks*4 + quad);
          acc = __builtin_amdgcn_mfma_f32_16x16x32_bf16(wf[ks], af, acc, 0, 0, 0);
        }
        #pragma unroll
        for (int i = 0; i < 4; ++i) nq[i] += acc[i]*acc[i];
      }
      f32x4 nv;
      #pragma unroll
      for (int i = 0; i < 4; ++i) nv[i] = sqrtf(nq[i]);
      stq(hbuf, 32, arow, NF + fb, pack4f(nv));
    }
  }
  __syncthreads();

  // ---- Phase B: ([s|n2] @ a1w)^T + bias, silu -> h1 (hbuf hi, after mid-bar) ----
  {
    const __hip_bfloat16* lb = blob;
    bf16x8 a1f[8];
    #pragma unroll
    for (int ks = 0; ks < 8; ++ks)
      a1f[ks] = *(const bf16x8*)&lb[OA1 + ((size_t)(ct*8 + ks)*64 + lane)*8];
    const f32x4 b1a4 = *(const f32x4*)&a1b[fb];
    f32x4 h[2];
    #pragma unroll
    for (int rt = 0; rt < 2; ++rt) {
      int arow = rt*16 + l15;
      f32x4 acc = {0.f,0.f,0.f,0.f};
      #pragma unroll
      for (int ks = 0; ks < 8; ++ks) {
        bf16x8 af = ldfrag(hbuf, 32, arow, ks*4 + quad);
        acc = __builtin_amdgcn_mfma_f32_16x16x32_bf16(a1f[ks], af, acc, 0, 0, 0);
      }
      #pragma unroll
      for (int i = 0; i < 4; ++i) {
        float x = acc[i] + b1a4[i];
        h[rt][i] = x / (1.0f + __expf(-x));
      }
    }
    __syncthreads();   // all reads of [s|n2] done -> safe to overwrite hi-half
    stq(hbuf, 32,      l15, NF + fb, pack4f(h[0]));
    stq(hbuf, 32, 16 + l15, NF + fb, pack4f(h[1]));
  }
  __syncthreads();

  // ---- Phase C(i): s1 = h1 @ a2w (s-half) -> hbuf lo; gate g in regs ----
  f32x4 g[2];
  {
    const __hip_bfloat16* lb = blob;
    {
      bf16x8 asf[4];
      #pragma unroll
      for (int ks = 0; ks < 4; ++ks)
        asf[ks] = *(const bf16x8*)&lb[OA2 + ((size_t)(ct*4 + ks)*64 + lane)*8];
      const f32x4 b2s4 = *(const f32x4*)&a2b[fb];
      #pragma unroll
      for (int rt = 0; rt < 2; ++rt) {
        int arow = rt*16 + l15;
        f32x4 hs = {0.f,0.f,0.f,0.f};
        #pragma unroll
        for (int ks = 0; ks < 4; ++ks) {
          bf16x8 af = ldfrag(hbuf, 32, arow, 16 + ks*4 + quad);   // h1 in hi-half
          hs = __builtin_amdgcn_mfma_f32_16x16x32_bf16(asf[ks], af, hs, 0, 0, 0);
        }
        f32x4 sv;
        #pragma unroll
        for (int i = 0; i < 4; ++i) sv[i] = hs[i] + b2s4[i];
        stq(hbuf, 32, arow, fb, pack4f(sv));   // lo-half write; s is dead
      }
    }
    {
      bf16x8 agf[4];
      #pragma unroll
      for (int ks = 0; ks < 4; ++ks)
        agf[ks] = *(const bf16x8*)&lb[OA2 + ((size_t)((ct+8)*4 + ks)*64 + lane)*8];
      const f32x4 b2g4 = *(const f32x4*)&a2b[NF + fb];
      #pragma unroll
      for (int rt = 0; rt < 2; ++rt) {
        int arow = rt*16 + l15;
        f32x4 hg = {0.f,0.f,0.f,0.f};
        #pragma unroll
        for (int ks = 0; ks < 4; ++ks) {
          bf16x8 af = ldfrag(hbuf, 32, arow, 16 + ks*4 + quad);
          hg = __builtin_amdgcn_mfma_f32_16x16x32_bf16(agf[ks], af, hg, 0, 0, 0);
        }
        #pragma unroll
        for (int i = 0; i < 4; ++i) g[rt][i] = hg[i] + b2g4[i];
      }
    }
  }

  // ---- Phase C(ii): rematerialize v1 = v @ w1 per plane, gate, write
  //      IN PLACE into vcur. read plane c -> barrier -> write plane c. ----
  {
    const __hip_bfloat16* lb = blob;
    bf16x8 wf[4];
    #pragma unroll
    for (int ks = 0; ks < 4; ++ks)
      wf[ks] = *(const bf16x8*)&lb[OW1 + ((size_t)(ct*4 + ks)*64 + lane)*8];
    #pragma unroll
    for (int c = 0; c < 3; ++c) {
      f32x4 acc0 = {0.f,0.f,0.f,0.f}, acc1 = {0.f,0.f,0.f,0.f};
      #pragma unroll
      for (int ks = 0; ks < 4; ++ks) {
        bf16x8 af0 = ldfrag(vcur + c*MT*NF, 16, l15,      ks*4 + quad);
        bf16x8 af1 = ldfrag(vcur + c*MT*NF, 16, 16 + l15, ks*4 + quad);
        acc0 = __builtin_amdgcn_mfma_f32_16x16x32_bf16(wf[ks], af0, acc0, 0, 0, 0);
        acc1 = __builtin_amdgcn_mfma_f32_16x16x32_bf16(wf[ks], af1, acc1, 0, 0, 0);
      }
      __syncthreads();          // all reads of plane c done
      f32x4 gv0, gv1;
      #pragma unroll
      for (int i = 0; i < 4; ++i) { gv0[i] = g[0][i]*acc0[i]; gv1[i] = g[1][i]*acc1[i]; }
      stq(vcur + c*MT*NF, 16, l15,      fb, pack4f(gv0));
      stq(vcur + c*MT*NF, 16, 16 + l15, fb, pack4f(gv1));
    }
  }
  __syncthreads();

  // ================= Layer 2 =================
  // ---- Phase A': (v1g @ w2')^T -> n2' (hbuf hi; h1 dead after C(i)) ----
  {
    const __hip_bfloat16* lb = blob + LAYER_SZ;
    bf16x8 wf[4];
    #pragma unroll
    for (int ks = 0; ks < 4; ++ks)
      wf[ks] = *(const bf16x8*)&lb[OW2 + ((size_t)(ct*4 + ks)*64 + lane)*8];
    #pragma unroll
    for (int rt = 0; rt < 2; ++rt) {
      int arow = rt*16 + l15;
      f32x4 nq = {0.f,0.f,0.f,0.f};
      #pragma unroll
      for (int c = 0; c < 3; ++c) {
        f32x4 acc = {0.f,0.f,0.f,0.f};
        #pragma unroll
        for (int ks = 0; ks < 4; ++ks) {
          bf16x8 af = ldfrag(vcur + c*MT*NF, 16, arow, ks*4 + quad);
          acc = __builtin_amdgcn_mfma_f32_16x16x32_bf16(wf[ks], af, acc, 0, 0, 0);
        }
        #pragma unroll
        for (int i = 0; i < 4; ++i) nq[i] += acc[i]*acc[i];
      }
      f32x4 nv;
      #pragma unroll
      for (int i = 0; i < 4; ++i) nv[i] = sqrtf(nq[i]);
      stq(hbuf, 32, arow, NF + fb, pack4f(nv));
    }
  }
  __syncthreads();

  // ---- Phase B' + folded head: ([s1|n2'] @ a1w')^T + bias, silu -> h1' in
  //      REGS; partial = h1' . u[fb..fb+3] -> padded LDS; reduce -> sc ----
  {
    const __hip_bfloat16* lb = blob + LAYER_SZ;
    bf16x8 a1f[8];
    #pragma unroll
    for (int ks = 0; ks < 8; ++ks)
      a1f[ks] = *(const bf16x8*)&lb[OA1 + ((size_t)(ct*8 + ks)*64 + lane)*8];
    const f32x4 b1g4 = *(const f32x4*)&a1b[NF + fb];
    const f32x4 u4   = *(const f32x4*)&uc[fb];
    float part[2];
    #pragma unroll
    for (int rt = 0; rt < 2; ++rt) {
      int arow = rt*16 + l15;
      f32x4 acc = {0.f,0.f,0.f,0.f};
      #pragma unroll
      for (int ks = 0; ks < 8; ++ks) {
        bf16x8 af = ldfrag(hbuf, 32, arow, ks*4 + quad);   // lo=s1, hi=n2'
        acc = __builtin_amdgcn_mfma_f32_16x16x32_bf16(a1f[ks], af, acc, 0, 0, 0);
      }
      float p = 0.f;
      #pragma unroll
      for (int i = 0; i < 4; ++i) {
        float x = acc[i] + b1g4[i];
        p += (x / (1.0f + __expf(-x))) * u4[i];
      }
      part[rt] = p;
    }
    __syncthreads();   // all reads of [s1|n2'] done -> hbuf reusable
    float* partf = (float*)hbuf;             // part[32][33] padded, 4224 B
    partf[(     l15)*33 + ct*4 + quad] = part[0];
    partf[(16 + l15)*33 + ct*4 + quad] = part[1];
  }
  __syncthreads();

  // ---- head reduce: sc[atom] = sum of 32 partials + const ----
  {
    const float* partf = (const float*)hbuf;
    int a   = tid >> 4;        // 32 atoms x 16 threads
    int sub = tid & 15;
    float p = partf[a*33 + sub] + partf[a*33 + sub + 16];
    p += __shfl_down(p, 8, 16);
    p += __shfl_down(p, 4, 16);
    p += __shfl_down(p, 2, 16);
    p += __shfl_down(p, 1, 16);
    if (sub == 0) sc[a0 + a] = p + uc[NF];
  }
}

// Stage 1: partials over 16 aligned chunks per graph (2048 blocks, float4 loads)
#define CHUNK 6256   // 16B-aligned chunk (6256*4 bytes); last chunk = 6160
__global__ __launch_bounds__(256)
void reduce_partial(const float* __restrict__ mask, const float* __restrict__ sc,
                    float* __restrict__ partial) {
  int b  = blockIdx.x >> 4;
  int ch = blockIdx.x & 15;
  int n0 = ch * CHUNK;
  int n1 = n0 + CHUNK; if (n1 > NATOMS) n1 = NATOMS;
  const float4* m4 = (const float4*)(mask + (size_t)b * NATOMS + n0);
  const float4* s4 = (const float4*)(sc + n0);
  int nq = (n1 - n0) >> 2;
  float acc = 0.f;
  for (int i = threadIdx.x; i < nq; i += 256) {
    float4 m = m4[i], s = s4[i];
    acc += m.x*s.x + m.y*s.y + m.z*s.z + m.w*s.w;
  }
  #pragma unroll
  for (int d = 32; d > 0; d >>= 1) acc += __shfl_down(acc, d, 64);
  __shared__ float red[4];
  if ((threadIdx.x & 63) == 0) red[threadIdx.x >> 6] = acc;
  __syncthreads();
  if (threadIdx.x == 0) partial[blockIdx.x] = red[0] + red[1] + red[2] + red[3];
}

__global__ void reduce_final(const float* __restrict__ partial, float* __restrict__ out) {
  int b = threadIdx.x;
  if (b < NGRAPH) {
    float s = 0.f;
    #pragma unroll
    for (int k = 0; k < 16; ++k) s += partial[b*16 + k];
    out[b] = s;
  }
}

extern "C" void kernel_launch(void* const* d_in, const int* in_sizes, int n_in,
                              void* d_out, int out_size, void* d_ws, size_t ws_size,
                              hipStream_t stream) {
  const float* s    = (const float*)d_in[0];
  const float* v    = (const float*)d_in[1];
  // d_in[2] = r, unused
  const float* mask = (const float*)d_in[3];
  const float* w1   = (const float*)d_in[4];
  const float* w2   = (const float*)d_in[5];
  const float* a1w  = (const float*)d_in[6];
  const float* a1b  = (const float*)d_in[7];
  const float* a2w  = (const float*)d_in[8];
  const float* a2b  = (const float*)d_in[9];
  const float* outw = (const float*)d_in[10];
  const float* outb = (const float*)d_in[11];

  char* ws = (char*)d_ws;
  __hip_bfloat16* blob = (__hip_bfloat16*)ws;                        // 384 KB
  float* sc      = (float*)(ws + (size_t)2*LAYER_SZ*2);              // 400 KB
  float* partial = (float*)(ws + (size_t)2*LAYER_SZ*2 + NATOMS*4);   // 8 KB
  float* uc      = (float*)(ws + (size_t)2*LAYER_SZ*2 + NATOMS*4 + NGRAPH*16*4); // 516 B

  prep_weights<<<97, 256, 0, stream>>>(w1, w2, a1w, a2w, a2b, outw, outb, blob, uc);
  fused_equiv<<<NBLK, NTHR, 0, stream>>>(s, v, blob, a1b, a2b, uc, sc);
  reduce_partial<<<NGRAPH*16, 256, 0, stream>>>(mask, sc, partial);
  reduce_final<<<1, 128, 0, stream>>>(partial, (float*)d_out);
}